// Round 2
// baseline (3846.383 us; speedup 1.0000x reference)
//
#include <hip/hip_runtime.h>
#include <hip/hip_bf16.h>

#define NU 100000
#define NT 300000
#define NM 10000

typedef __hip_bfloat16 bf16;

__device__ __forceinline__ float toF(float v) { return v; }
__device__ __forceinline__ float toF(bf16 v)  { return __bfloat162float(v); }

// ---------- helpers ----------
__device__ __forceinline__ void atomicMaxF(float* addr, float v) {
    // monotonic int/uint trick; init value is -inf
    if (v >= 0.f) atomicMax((int*)addr, __float_as_int(v));
    else          atomicMin((unsigned int*)addr, __float_as_uint(v));
}

__global__ void k_zero(float* __restrict__ p, int n) {
    int i = blockIdx.x * 256 + threadIdx.x;
    if (i < n) p[i] = 0.f;
}

// ---------- wa[l,r,k,j]: fold W @ att into per-node GEMV weights ----------
// wa[lr*512 + k*8 + j]; j in 0..3 -> src head j, j in 4..7 -> dst head j-4
__global__ void k_wa(const float* __restrict__ lin_w, const float* __restrict__ att_s,
                     const float* __restrict__ att_d, float* __restrict__ wa) {
    int i = blockIdx.x * 256 + threadIdx.x;
    if (i >= 2 * 7 * 64 * 8) return;
    int j = i & 7;
    int k = (i >> 3) & 63;
    int lr = i >> 9;
    int h = j & 3;
    const float* a = (j < 4 ? att_s : att_d) + lr * 64 + h * 16;
    const float* Wp = lin_w + (size_t)lr * 4096 + k * 64 + h * 16;
    float s = 0.f;
#pragma unroll
    for (int c = 0; c < 16; c++) s += Wp[c] * a[c];
    wa[i] = s;
}

// ---------- x[N,K] @ W[K,64] (+bias) -> out[N,64] bf16, fp32 math ----------
template <typename TIN>
__global__ void k_proj(const TIN* __restrict__ x, const float* __restrict__ W,
                       const float* __restrict__ bias, bf16* __restrict__ out,
                       int N, int K) {
    __shared__ float Ws[64 * 64];
    __shared__ float xs[32 * 64];
    int tid = threadIdx.x;
    int r0 = blockIdx.x << 5;
    for (int i = tid; i < K * 64; i += 256) Ws[i] = W[i];
    for (int i = tid; i < 32 * K; i += 256) {
        int row = i / K, col = i - row * K;
        int n = r0 + row;
        xs[(row << 6) + col] = (n < N) ? toF(x[(size_t)n * K + col]) : 0.f;
    }
    __syncthreads();
    int c = tid & 63;
    float bv = bias ? bias[c] : 0.f;
    for (int rr = tid >> 6; rr < 32; rr += 4) {
        int n = r0 + rr;
        if (n >= N) return;
        float acc = bv;
#pragma unroll 16
        for (int k = 0; k < K; k++) acc = fmaf(xs[(rr << 6) + k], Ws[(k << 6) + c], acc);
        out[(size_t)n * 64 + c] = __float2bfloat16(acc);
    }
}

// ---------- alpha_{s,d}[n,h] = x[n,:] @ wa[:, j] ----------
__global__ void k_alpha(const bf16* __restrict__ x, const float* __restrict__ wa,
                        float* __restrict__ aS, float* __restrict__ aD,
                        int N, int doS, int doD) {
    __shared__ float xs[32 * 64];
    __shared__ float was[512];
    int tid = threadIdx.x;
    int r0 = blockIdx.x << 5;
    was[tid] = wa[tid];
    was[tid + 256] = wa[tid + 256];
    for (int i = tid; i < 2048; i += 256) {
        int row = i >> 6, col = i & 63;
        int n = r0 + row;
        xs[i] = (n < N) ? toF(x[(size_t)n * 64 + col]) : 0.f;
    }
    __syncthreads();
    int row = tid >> 3, j = tid & 7;
    int n = r0 + row;
    if (n >= N) return;
    float acc = 0.f;
#pragma unroll
    for (int k = 0; k < 64; k++) acc = fmaf(xs[(row << 6) + k], was[(k << 3) + j], acc);
    if (j < 4) { if (doS) aS[n * 4 + j] = acc; }
    else if (doD) aD[n * 4 + (j - 4)] = acc;
}

__global__ void k_init(float* __restrict__ amax, float* __restrict__ denom, int n4) {
    int i = blockIdx.x * 256 + threadIdx.x;
    if (i < n4) { amax[i] = -INFINITY; denom[i] = 0.f; }
}

// ---------- edge pass 1: leaky-relu(alpha) + segment max ----------
__global__ void k_edge1(const int* __restrict__ ei, int E, const float* __restrict__ aS,
                        const float* __restrict__ aD, float* __restrict__ al,
                        float* __restrict__ amax) {
    int i = blockIdx.x * 256 + threadIdx.x;
    if (i >= E * 4) return;
    int e = i >> 2, h = i & 3;
    int s = ei[e], d = ei[E + e];
    float a = aS[s * 4 + h] + aD[d * 4 + h];
    a = (a >= 0.f) ? a : 0.2f * a;
    al[i] = a;
    atomicMaxF(&amax[d * 4 + h], a);
}

// ---------- edge pass 2: exp + segment sum ----------
__global__ void k_edge2(const int* __restrict__ ei, int E, float* __restrict__ al,
                        const float* __restrict__ amax, float* __restrict__ denom) {
    int i = blockIdx.x * 256 + threadIdx.x;
    if (i >= E * 4) return;
    int e = i >> 2, h = i & 3;
    int d = ei[E + e];
    float ex = __expf(al[i] - amax[d * 4 + h]);
    al[i] = ex;
    atomicAdd(&denom[d * 4 + h], ex);
}

// ---------- edge pass 3: weighted message scatter ----------
__global__ void k_edge3(const int* __restrict__ ei, int E, const bf16* __restrict__ hs,
                        const float* __restrict__ ex, const float* __restrict__ denom,
                        float* __restrict__ acc) {
    long long i = (long long)blockIdx.x * 256 + threadIdx.x;
    if (i >= (long long)E * 64) return;
    int e = (int)(i >> 6), c = (int)(i & 63);
    int s = ei[e], d = ei[E + e];
    int h = c >> 4;
    float w = ex[e * 4 + h] / (denom[d * 4 + h] + 1e-16f);
    atomicAdd(&acc[(size_t)d * 64 + c], toF(hs[(size_t)s * 64 + c]) * w);
}

// ---------- finalize: acc + sum(biases), relu -> cur (bf16) ----------
__global__ void k_fin(const float* __restrict__ acc, const float* __restrict__ cb,
                      int ra, int rb, int rc, bf16* __restrict__ cur, int N) {
    int i = blockIdx.x * 256 + threadIdx.x;
    if (i >= N * 64) return;
    int c = i & 63;
    float b = cb[ra * 64 + c];
    if (rb >= 0) b += cb[rb * 64 + c];
    if (rc >= 0) b += cb[rc * 64 + c];
    float v = acc[i] + b;
    cur[i] = __float2bfloat16(v > 0.f ? v : 0.f);
}

// ---------- classifier: relu(t@w1+b1)@w2+b2, fused ----------
__global__ void k_cls(const bf16* __restrict__ t, const float* __restrict__ w1,
                      const float* __restrict__ b1, const float* __restrict__ w2,
                      const float* __restrict__ b2, float* __restrict__ out) {
    __shared__ float w1s[64 * 32];
    __shared__ float w2s[64];
    __shared__ float b1s[32];
    __shared__ float b2s[2];
    __shared__ float ts[8 * 64];
    int tid = threadIdx.x;
    for (int i = tid; i < 2048; i += 256) w1s[i] = w1[i];
    if (tid < 64) w2s[tid] = w2[tid];
    if (tid < 32) b1s[tid] = b1[tid];
    if (tid < 2) b2s[tid] = b2[tid];
    int n0 = blockIdx.x << 3;
    for (int i = tid; i < 512; i += 256) {
        int row = i >> 6, col = i & 63;
        ts[i] = toF(t[(size_t)(n0 + row) * 64 + col]);
    }
    __syncthreads();
    int lane = tid & 31;
    int row = tid >> 5;
    float h = b1s[lane];
#pragma unroll 8
    for (int k = 0; k < 64; k++) h = fmaf(ts[(row << 6) + k], w1s[(k << 5) + lane], h);
    h = h > 0.f ? h : 0.f;
    float o0 = h * w2s[lane * 2 + 0];
    float o1 = h * w2s[lane * 2 + 1];
#pragma unroll
    for (int off = 16; off; off >>= 1) {
        o0 += __shfl_down(o0, off, 32);
        o1 += __shfl_down(o1, off, 32);
    }
    if (lane == 0) {
        int n = n0 + row;
        out[(size_t)n * 2 + 0] = o0 + b2s[0];
        out[(size_t)n * 2 + 1] = o1 + b2s[1];
    }
}

extern "C" void kernel_launch(void* const* d_in, const int* in_sizes, int n_in,
                              void* d_out, int out_size, void* d_ws, size_t ws_size,
                              hipStream_t stream) {
    (void)n_in; (void)out_size;
    const float* x_user  = (const float*)d_in[0];
    const float* x_tx    = (const float*)d_in[1];
    const float* x_merch = (const float*)d_in[2];
    const int* ei[7] = { (const int*)d_in[3], (const int*)d_in[4], (const int*)d_in[5],
                         (const int*)d_in[6], (const int*)d_in[7], (const int*)d_in[8],
                         (const int*)d_in[9] };
    int E[7];
    for (int r = 0; r < 7; r++) E[r] = in_sizes[3 + r] / 2;
    const float* Win_user  = (const float*)d_in[10];
    const float* bin_user  = (const float*)d_in[11];
    const float* Win_tx    = (const float*)d_in[12];
    const float* bin_tx    = (const float*)d_in[13];
    const float* Win_merch = (const float*)d_in[14];
    const float* bin_merch = (const float*)d_in[15];
    const float* lin_w     = (const float*)d_in[16];
    const float* att_src   = (const float*)d_in[17];
    const float* att_dst   = (const float*)d_in[18];
    const float* conv_bias = (const float*)d_in[19];
    const float* cls_w1    = (const float*)d_in[20];
    const float* cls_b1    = (const float*)d_in[21];
    const float* cls_w2    = (const float*)d_in[22];
    const float* cls_b2    = (const float*)d_in[23];

    // ---- workspace layout (offsets first, then guard) ----
    size_t off = 0;
    auto alloc = [&](size_t bytes) { size_t q = off; off += (bytes + 255) & ~(size_t)255; return q; };
    size_t o_cur_u = alloc((size_t)NU * 64 * 2);       // bf16
    size_t o_cur_t = alloc((size_t)NT * 64 * 2);       // bf16
    size_t o_cur_m = alloc((size_t)NM * 64 * 2);       // bf16
    size_t o_nxt_u = alloc((size_t)NU * 64 * 4);       // f32
    size_t o_nxt_t = alloc((size_t)NT * 64 * 4);       // f32
    size_t o_nxt_m = alloc((size_t)NM * 64 * 4);       // f32
    size_t o_hs    = alloc((size_t)NT * 64 * 2);       // bf16
    size_t o_aS    = alloc((size_t)NT * 4 * 4);
    size_t o_aD    = alloc((size_t)NT * 4 * 4);
    size_t o_amax  = alloc((size_t)NT * 4 * 4);
    size_t o_denom = alloc((size_t)NT * 4 * 4);
    size_t o_al    = alloc((size_t)600000 * 4 * 4);
    size_t o_wa    = alloc((size_t)2 * 7 * 64 * 8 * 4);
    if (off > ws_size) return;  // scratch too small: fail cleanly (no device fault)

    char* base = (char*)d_ws;
    bf16*  cur_u = (bf16*)(base + o_cur_u);
    bf16*  cur_t = (bf16*)(base + o_cur_t);
    bf16*  cur_m = (bf16*)(base + o_cur_m);
    float* nxt_u = (float*)(base + o_nxt_u);
    float* nxt_t = (float*)(base + o_nxt_t);
    float* nxt_m = (float*)(base + o_nxt_m);
    bf16*  hs    = (bf16*)(base + o_hs);
    float* aS    = (float*)(base + o_aS);
    float* aD    = (float*)(base + o_aD);
    float* amax  = (float*)(base + o_amax);
    float* denom = (float*)(base + o_denom);
    float* al    = (float*)(base + o_al);
    float* wa    = (float*)(base + o_wa);

    k_wa<<<(7168 + 255) / 256, 256, 0, stream>>>(lin_w, att_src, att_dst, wa);
    k_proj<float><<<(NU + 31) / 32, 256, 0, stream>>>(x_user, Win_user, bin_user, cur_u, NU, 32);
    k_proj<float><<<(NT + 31) / 32, 256, 0, stream>>>(x_tx, Win_tx, bin_tx, cur_t, NT, 64);
    k_proj<float><<<(NM + 31) / 32, 256, 0, stream>>>(x_merch, Win_merch, bin_merch, cur_m, NM, 16);

    struct CV { bf16* src; int Ns; bf16* dst; int Nd; float* acc; };
    CV cv[7] = {
        { cur_u, NU, cur_t, NT, nxt_t },   // r0: u->t
        { cur_t, NT, cur_u, NU, nxt_u },   // r1: t->u
        { cur_m, NM, cur_t, NT, nxt_t },   // r2: m->t
        { cur_t, NT, cur_m, NM, nxt_m },   // r3: t->m
        { cur_u, NU, cur_u, NU, nxt_u },   // r4: u->u
        { cur_m, NM, cur_m, NM, nxt_m },   // r5: m->m
        { cur_t, NT, cur_t, NT, nxt_t },   // r6: t->t
    };

    for (int l = 0; l < 2; l++) {
        k_zero<<<(NU * 64 + 255) / 256, 256, 0, stream>>>(nxt_u, NU * 64);
        k_zero<<<(NT * 64 + 255) / 256, 256, 0, stream>>>(nxt_t, NT * 64);
        k_zero<<<(NM * 64 + 255) / 256, 256, 0, stream>>>(nxt_m, NM * 64);
        for (int r = 0; r < 7; r++) {
            CV& c = cv[r];
            const float* W = lin_w + (size_t)(l * 7 + r) * 4096;
            const float* war = wa + (size_t)(l * 7 + r) * 512;
            k_proj<bf16><<<(c.Ns + 31) / 32, 256, 0, stream>>>(c.src, W, nullptr, hs, c.Ns, 64);
            if (c.src == c.dst) {
                k_alpha<<<(c.Ns + 31) / 32, 256, 0, stream>>>(c.src, war, aS, aD, c.Ns, 1, 1);
            } else {
                k_alpha<<<(c.Ns + 31) / 32, 256, 0, stream>>>(c.src, war, aS, aD, c.Ns, 1, 0);
                k_alpha<<<(c.Nd + 31) / 32, 256, 0, stream>>>(c.dst, war, aS, aD, c.Nd, 0, 1);
            }
            int n4 = c.Nd * 4;
            k_init<<<(n4 + 255) / 256, 256, 0, stream>>>(amax, denom, n4);
            int e4 = E[r] * 4;
            k_edge1<<<(e4 + 255) / 256, 256, 0, stream>>>(ei[r], E[r], aS, aD, al, amax);
            k_edge2<<<(e4 + 255) / 256, 256, 0, stream>>>(ei[r], E[r], al, amax, denom);
            long long e64 = (long long)E[r] * 64;
            k_edge3<<<(int)((e64 + 255) / 256), 256, 0, stream>>>(ei[r], E[r], hs, al, denom, c.acc);
        }
        const float* cb = conv_bias + (size_t)l * 7 * 64;
        k_fin<<<(NT * 64 + 255) / 256, 256, 0, stream>>>(nxt_t, cb, 0, 2, 6, cur_t, NT);
        k_fin<<<(NU * 64 + 255) / 256, 256, 0, stream>>>(nxt_u, cb, 1, 4, -1, cur_u, NU);
        k_fin<<<(NM * 64 + 255) / 256, 256, 0, stream>>>(nxt_m, cb, 3, 5, -1, cur_m, NM);
    }
    k_cls<<<NT / 8, 256, 0, stream>>>(cur_t, cls_w1, cls_b1, cls_w2, cls_b2, (float*)d_out);
}

// Round 3
// 3218.982 us; speedup vs baseline: 1.1949x; 1.1949x over previous
//
#include <hip/hip_runtime.h>
#include <hip/hip_bf16.h>

#define NU 100000
#define NT 300000
#define NM 10000

typedef __hip_bfloat16 bf16;

__device__ __forceinline__ float toF(float v) { return v; }
__device__ __forceinline__ float toF(bf16 v)  { return __bfloat162float(v); }

// ================= CSR build =================
__global__ void k_zero_i(int* __restrict__ p, int n) {
    int i = blockIdx.x * 256 + threadIdx.x;
    if (i < n) p[i] = 0;
}

__global__ void k_hist(const int* __restrict__ ei, int E, int* __restrict__ cnt) {
    int e = blockIdx.x * 256 + threadIdx.x;
    if (e < E) atomicAdd(&cnt[ei[E + e]], 1);
}

// 3-phase exclusive scan over n elements (grid covers n+1 outputs; out[n]=total)
__global__ void k_scan1(const int* __restrict__ cnt, int n, int* __restrict__ bsum) {
    __shared__ int sh[256];
    int i = blockIdx.x * 256 + threadIdx.x;
    sh[threadIdx.x] = (i < n) ? cnt[i] : 0;
    __syncthreads();
    for (int o = 128; o; o >>= 1) {
        if (threadIdx.x < o) sh[threadIdx.x] += sh[threadIdx.x + o];
        __syncthreads();
    }
    if (threadIdx.x == 0) bsum[blockIdx.x] = sh[0];
}

__global__ void k_scan2(int* __restrict__ bsum, int nb) {  // 1 block, 256 thr
    __shared__ int sh[256];
    __shared__ int carry;
    if (threadIdx.x == 0) carry = 0;
    __syncthreads();
    for (int base = 0; base < nb; base += 256) {
        int i = base + threadIdx.x;
        int v = (i < nb) ? bsum[i] : 0;
        sh[threadIdx.x] = v;
        __syncthreads();
        for (int o = 1; o < 256; o <<= 1) {
            int t = (threadIdx.x >= o) ? sh[threadIdx.x - o] : 0;
            __syncthreads();
            sh[threadIdx.x] += t;
            __syncthreads();
        }
        if (i < nb) bsum[i] = carry + sh[threadIdx.x] - v;  // exclusive
        __syncthreads();
        if (threadIdx.x == 255) carry += sh[255];
        __syncthreads();
    }
}

__global__ void k_scan3(const int* __restrict__ cnt, int n, const int* __restrict__ bsum,
                        int* __restrict__ out) {
    __shared__ int sh[256];
    int i = blockIdx.x * 256 + threadIdx.x;
    int v = (i < n) ? cnt[i] : 0;
    sh[threadIdx.x] = v;
    __syncthreads();
    for (int o = 1; o < 256; o <<= 1) {
        int t = (threadIdx.x >= o) ? sh[threadIdx.x - o] : 0;
        __syncthreads();
        sh[threadIdx.x] += t;
        __syncthreads();
    }
    if (i <= n) out[i] = bsum[blockIdx.x] + sh[threadIdx.x] - v;
}

__global__ void k_fill(const int* __restrict__ ei, int E, const int* __restrict__ rowptr,
                       int* __restrict__ cnt, int* __restrict__ col) {
    int e = blockIdx.x * 256 + threadIdx.x;
    if (e >= E) return;
    int d = ei[E + e];
    int pos = rowptr[d] + atomicAdd(&cnt[d], 1);
    col[pos] = ei[e];
}

// ================= dense small kernels =================
// wa[lr*512 + k*8 + j]; j 0..3 -> src head j, 4..7 -> dst head j-4
__global__ void k_wa(const float* __restrict__ lin_w, const float* __restrict__ att_s,
                     const float* __restrict__ att_d, float* __restrict__ wa) {
    int i = blockIdx.x * 256 + threadIdx.x;
    if (i >= 2 * 7 * 64 * 8) return;
    int j = i & 7;
    int k = (i >> 3) & 63;
    int lr = i >> 9;
    int h = j & 3;
    const float* a = (j < 4 ? att_s : att_d) + lr * 64 + h * 16;
    const float* Wp = lin_w + (size_t)lr * 4096 + k * 64 + h * 16;
    float s = 0.f;
#pragma unroll
    for (int c = 0; c < 16; c++) s += Wp[c] * a[c];
    wa[i] = s;
}

// x[N,K] @ W[K,64] (+bias) -> out[N,64] bf16, fp32 math
template <typename TIN>
__global__ void k_proj(const TIN* __restrict__ x, const float* __restrict__ W,
                       const float* __restrict__ bias, bf16* __restrict__ out,
                       int N, int K) {
    __shared__ float Ws[64 * 64];
    __shared__ float xs[32 * 64];
    int tid = threadIdx.x;
    int r0 = blockIdx.x << 5;
    for (int i = tid; i < K * 64; i += 256) Ws[i] = W[i];
    for (int i = tid; i < 32 * K; i += 256) {
        int row = i / K, col = i - row * K;
        int n = r0 + row;
        xs[(row << 6) + col] = (n < N) ? toF(x[(size_t)n * K + col]) : 0.f;
    }
    __syncthreads();
    int c = tid & 63;
    float bv = bias ? bias[c] : 0.f;
    for (int rr = tid >> 6; rr < 32; rr += 4) {
        int n = r0 + rr;
        if (n >= N) return;
        float acc = bv;
#pragma unroll 16
        for (int k = 0; k < K; k++) acc = fmaf(xs[(rr << 6) + k], Ws[(k << 6) + c], acc);
        out[(size_t)n * 64 + c] = __float2bfloat16(acc);
    }
}

// alpha_{s,d}[n,h] = x[n,:] @ wa[:, j]
__global__ void k_alpha(const bf16* __restrict__ x, const float* __restrict__ wa,
                        float* __restrict__ aS, float* __restrict__ aD,
                        int N, int doS, int doD) {
    __shared__ float xs[32 * 64];
    __shared__ float was[512];
    int tid = threadIdx.x;
    int r0 = blockIdx.x << 5;
    was[tid] = wa[tid];
    was[tid + 256] = wa[tid + 256];
    for (int i = tid; i < 2048; i += 256) {
        int row = i >> 6, col = i & 63;
        int n = r0 + row;
        xs[i] = (n < N) ? toF(x[(size_t)n * 64 + col]) : 0.f;
    }
    __syncthreads();
    int row = tid >> 3, j = tid & 7;
    int n = r0 + row;
    if (n >= N) return;
    float acc = 0.f;
#pragma unroll
    for (int k = 0; k < 64; k++) acc = fmaf(xs[(row << 6) + k], was[(k << 3) + j], acc);
    if (j < 4) { if (doS) aS[n * 4 + j] = acc; }
    else if (doD) aD[n * 4 + (j - 4)] = acc;
}

// ================= fused GAT aggregation: wave per dst node =================
__device__ __forceinline__ void gat_rel(const int* __restrict__ rowptr,
                                        const int* __restrict__ col,
                                        const float* __restrict__ aS,
                                        const float* __restrict__ aD,
                                        const bf16* __restrict__ hs,
                                        int node, int lane, float& acc) {
    int beg = rowptr[node], end = rowptr[node + 1];
    if (beg == end) return;
    int h = lane & 3;
    float ad = aD[node * 4 + h];
    // phase 1: per-head max (lane = j*4+h, j strides edges)
    float mx = -INFINITY;
    for (int i = beg + (lane >> 2); i < end; i += 16) {
        float a = aS[col[i] * 4 + h] + ad;
        a = (a >= 0.f) ? a : 0.2f * a;
        mx = fmaxf(mx, a);
    }
    mx = fmaxf(mx, __shfl_xor(mx, 4));
    mx = fmaxf(mx, __shfl_xor(mx, 8));
    mx = fmaxf(mx, __shfl_xor(mx, 16));
    mx = fmaxf(mx, __shfl_xor(mx, 32));
    // phase 2: denom
    float dn = 0.f;
    for (int i = beg + (lane >> 2); i < end; i += 16) {
        float a = aS[col[i] * 4 + h] + ad;
        a = (a >= 0.f) ? a : 0.2f * a;
        dn += __expf(a - mx);
    }
    dn += __shfl_xor(dn, 4);
    dn += __shfl_xor(dn, 8);
    dn += __shfl_xor(dn, 16);
    dn += __shfl_xor(dn, 32);
    // redistribute per-head stats to channel lanes (lane c -> head c>>4; lane h' holds head h')
    int hc = lane >> 4;
    float mh  = __shfl(mx, hc);
    float rdh = 1.f / (__shfl(dn, hc) + 1e-16f);
    float adh = __shfl(ad, hc);
    // phase 3: aggregate (lane = channel)
    for (int i = beg; i < end; i++) {
        int s = col[i];
        float a = aS[s * 4 + hc] + adh;
        a = (a >= 0.f) ? a : 0.2f * a;
        float w = __expf(a - mh) * rdh;
        acc = fmaf(toF(hs[(size_t)s * 64 + lane]), w, acc);
    }
}

__global__ void k_gat(const int* rp0, const int* c0, const float* aS0, const float* aD0, const bf16* h0,
                      const int* rp1, const int* c1, const float* aS1, const float* aD1, const bf16* h1,
                      const int* rp2, const int* c2, const float* aS2, const float* aD2, const bf16* h2,
                      const float* __restrict__ cb, int b0, int b1, int b2,
                      bf16* __restrict__ out, int Nd) {
    int node = blockIdx.x * 4 + (threadIdx.x >> 6);
    if (node >= Nd) return;
    int lane = threadIdx.x & 63;
    float acc = cb[b0 * 64 + lane];
    if (b1 >= 0) acc += cb[b1 * 64 + lane];
    if (b2 >= 0) acc += cb[b2 * 64 + lane];
    gat_rel(rp0, c0, aS0, aD0, h0, node, lane, acc);
    if (rp1) gat_rel(rp1, c1, aS1, aD1, h1, node, lane, acc);
    if (rp2) gat_rel(rp2, c2, aS2, aD2, h2, node, lane, acc);
    out[(size_t)node * 64 + lane] = __float2bfloat16(acc > 0.f ? acc : 0.f);
}

// ================= classifier =================
__global__ void k_cls(const bf16* __restrict__ t, const float* __restrict__ w1,
                      const float* __restrict__ b1, const float* __restrict__ w2,
                      const float* __restrict__ b2, float* __restrict__ out) {
    __shared__ float w1s[64 * 32];
    __shared__ float w2s[64];
    __shared__ float b1s[32];
    __shared__ float b2s[2];
    __shared__ float ts[8 * 64];
    int tid = threadIdx.x;
    for (int i = tid; i < 2048; i += 256) w1s[i] = w1[i];
    if (tid < 64) w2s[tid] = w2[tid];
    if (tid < 32) b1s[tid] = b1[tid];
    if (tid < 2) b2s[tid] = b2[tid];
    int n0 = blockIdx.x << 3;
    for (int i = tid; i < 512; i += 256) {
        int row = i >> 6, col = i & 63;
        ts[i] = toF(t[(size_t)(n0 + row) * 64 + col]);
    }
    __syncthreads();
    int lane = tid & 31;
    int row = tid >> 5;
    float h = b1s[lane];
#pragma unroll 8
    for (int k = 0; k < 64; k++) h = fmaf(ts[(row << 6) + k], w1s[(k << 5) + lane], h);
    h = h > 0.f ? h : 0.f;
    float o0 = h * w2s[lane * 2 + 0];
    float o1 = h * w2s[lane * 2 + 1];
#pragma unroll
    for (int off = 16; off; off >>= 1) {
        o0 += __shfl_down(o0, off, 32);
        o1 += __shfl_down(o1, off, 32);
    }
    if (lane == 0) {
        int n = n0 + row;
        out[(size_t)n * 2 + 0] = o0 + b2s[0];
        out[(size_t)n * 2 + 1] = o1 + b2s[1];
    }
}

extern "C" void kernel_launch(void* const* d_in, const int* in_sizes, int n_in,
                              void* d_out, int out_size, void* d_ws, size_t ws_size,
                              hipStream_t stream) {
    (void)n_in; (void)out_size;
    const float* x_user  = (const float*)d_in[0];
    const float* x_tx    = (const float*)d_in[1];
    const float* x_merch = (const float*)d_in[2];
    const int* ei[7];
    int E[7];
    for (int r = 0; r < 7; r++) { ei[r] = (const int*)d_in[3 + r]; E[r] = in_sizes[3 + r] / 2; }
    const float* Win_user  = (const float*)d_in[10];
    const float* bin_user  = (const float*)d_in[11];
    const float* Win_tx    = (const float*)d_in[12];
    const float* bin_tx    = (const float*)d_in[13];
    const float* Win_merch = (const float*)d_in[14];
    const float* bin_merch = (const float*)d_in[15];
    const float* lin_w     = (const float*)d_in[16];
    const float* att_src   = (const float*)d_in[17];
    const float* att_dst   = (const float*)d_in[18];
    const float* conv_bias = (const float*)d_in[19];
    const float* cls_w1    = (const float*)d_in[20];
    const float* cls_b1    = (const float*)d_in[21];
    const float* cls_w2    = (const float*)d_in[22];
    const float* cls_b2    = (const float*)d_in[23];

    // rel r: src_type, dst_type (0=u,1=t,2=m)
    const int src_type[7] = {0, 1, 2, 1, 0, 2, 1};
    const int dst_type[7] = {1, 0, 1, 2, 0, 2, 1};
    const int N_of[3] = {NU, NT, NM};

    // ---- workspace layout ----
    size_t off = 0;
    auto alloc = [&](size_t bytes) { size_t q = off; off += (bytes + 255) & ~(size_t)255; return q; };
    size_t o_a[3], o_b[3], o_hs[3], o_aS[3];
    for (int tpe = 0; tpe < 3; tpe++) o_a[tpe]  = alloc((size_t)N_of[tpe] * 64 * 2);
    for (int tpe = 0; tpe < 3; tpe++) o_b[tpe]  = alloc((size_t)N_of[tpe] * 64 * 2);
    for (int tpe = 0; tpe < 3; tpe++) o_hs[tpe] = alloc((size_t)N_of[tpe] * 64 * 2);
    for (int tpe = 0; tpe < 3; tpe++) o_aS[tpe] = alloc((size_t)N_of[tpe] * 4 * 4);
    size_t o_aD[3];
    for (int j = 0; j < 3; j++) o_aD[j] = alloc((size_t)NT * 4 * 4);
    size_t o_rp[7], o_col[7];
    for (int r = 0; r < 7; r++) o_rp[r]  = alloc(((size_t)N_of[dst_type[r]] + 1) * 4);
    for (int r = 0; r < 7; r++) o_col[r] = alloc((size_t)E[r] * 4);
    size_t o_cnt  = alloc((size_t)NT * 4);
    size_t o_bsum = alloc((size_t)4096 * 4);
    size_t o_wa   = alloc((size_t)2 * 7 * 64 * 8 * 4);
    if (off > ws_size) return;  // fail cleanly

    char* base = (char*)d_ws;
    bf16* A[3], *B[3], *hsS[3];
    float* aSS[3];
    for (int tpe = 0; tpe < 3; tpe++) {
        A[tpe] = (bf16*)(base + o_a[tpe]);
        B[tpe] = (bf16*)(base + o_b[tpe]);
        hsS[tpe] = (bf16*)(base + o_hs[tpe]);
        aSS[tpe] = (float*)(base + o_aS[tpe]);
    }
    float* aDS[3];
    for (int j = 0; j < 3; j++) aDS[j] = (float*)(base + o_aD[j]);
    int* rp[7]; int* col[7];
    for (int r = 0; r < 7; r++) { rp[r] = (int*)(base + o_rp[r]); col[r] = (int*)(base + o_col[r]); }
    int* cnt  = (int*)(base + o_cnt);
    int* bsum = (int*)(base + o_bsum);
    float* wa = (float*)(base + o_wa);

    // ---- build CSR per relation (once per call) ----
    for (int r = 0; r < 7; r++) {
        int Nd = N_of[dst_type[r]];
        int nb = (Nd + 1 + 255) / 256;  // scan grid covers Nd+1 outputs
        k_zero_i<<<(Nd + 255) / 256, 256, 0, stream>>>(cnt, Nd);
        k_hist<<<(E[r] + 255) / 256, 256, 0, stream>>>(ei[r], E[r], cnt);
        k_scan1<<<nb, 256, 0, stream>>>(cnt, Nd, bsum);
        k_scan2<<<1, 256, 0, stream>>>(bsum, nb);
        k_scan3<<<nb, 256, 0, stream>>>(cnt, Nd, bsum, rp[r]);
        k_zero_i<<<(Nd + 255) / 256, 256, 0, stream>>>(cnt, Nd);
        k_fill<<<(E[r] + 255) / 256, 256, 0, stream>>>(ei[r], E[r], rp[r], cnt, col[r]);
    }

    k_wa<<<(7168 + 255) / 256, 256, 0, stream>>>(lin_w, att_src, att_dst, wa);
    k_proj<float><<<(NU + 31) / 32, 256, 0, stream>>>(x_user, Win_user, bin_user, A[0], NU, 32);
    k_proj<float><<<(NT + 31) / 32, 256, 0, stream>>>(x_tx, Win_tx, bin_tx, A[1], NT, 64);
    k_proj<float><<<(NM + 31) / 32, 256, 0, stream>>>(x_merch, Win_merch, bin_merch, A[2], NM, 16);

    // groups by dst type: t <- {ut, mt, tt}; u <- {tu, uu}; m <- {tm, mm}
    const int grp_dst[3]     = {1, 0, 2};
    const int grp_rels[3][3] = {{0, 2, 6}, {1, 4, -1}, {3, 5, -1}};

    for (int l = 0; l < 2; l++) {
        bf16** cur = (l == 0) ? A : B;
        bf16** nxt = (l == 0) ? B : A;
        const float* cb = conv_bias + (size_t)l * 7 * 64;
        for (int g = 0; g < 3; g++) {
            int dt = grp_dst[g];
            int Nd = N_of[dt];
            const int* grp = grp_rels[g];
            // per-relation projections + alphas
            for (int j = 0; j < 3; j++) {
                int r = grp[j];
                if (r < 0) break;
                int st = src_type[r];
                const float* W   = lin_w + (size_t)(l * 7 + r) * 4096;
                const float* war = wa + (size_t)(l * 7 + r) * 512;
                k_proj<bf16><<<(N_of[st] + 31) / 32, 256, 0, stream>>>(cur[st], W, nullptr, hsS[st], N_of[st], 64);
                if (st == dt) {
                    k_alpha<<<(N_of[st] + 31) / 32, 256, 0, stream>>>(cur[st], war, aSS[st], aDS[j], N_of[st], 1, 1);
                } else {
                    k_alpha<<<(N_of[st] + 31) / 32, 256, 0, stream>>>(cur[st], war, aSS[st], nullptr, N_of[st], 1, 0);
                    k_alpha<<<(Nd + 31) / 32, 256, 0, stream>>>(cur[dt], war, nullptr, aDS[j], Nd, 0, 1);
                }
            }
            // fused aggregation
            int r0 = grp[0], r1 = grp[1], r2 = grp[2];
            k_gat<<<(Nd + 3) / 4, 256, 0, stream>>>(
                rp[r0], col[r0], aSS[src_type[r0]], aDS[0], hsS[src_type[r0]],
                r1 >= 0 ? rp[r1] : nullptr, r1 >= 0 ? col[r1] : nullptr,
                r1 >= 0 ? aSS[src_type[r1]] : nullptr, aDS[1], r1 >= 0 ? hsS[src_type[r1]] : nullptr,
                r2 >= 0 ? rp[r2] : nullptr, r2 >= 0 ? col[r2] : nullptr,
                r2 >= 0 ? aSS[src_type[r2]] : nullptr, aDS[2], r2 >= 0 ? hsS[src_type[r2]] : nullptr,
                cb, r0, r1, r2, nxt[dt], Nd);
        }
    }
    k_cls<<<NT / 8, 256, 0, stream>>>(A[1], cls_w1, cls_b1, cls_w2, cls_b2, (float*)d_out);
}

// Round 5
// 1983.336 us; speedup vs baseline: 1.9394x; 1.6230x over previous
//
#include <hip/hip_runtime.h>
#include <hip/hip_bf16.h>

#define NU 100000
#define NT 300000
#define NM 10000

typedef __hip_bfloat16 bf16;
typedef __attribute__((ext_vector_type(8))) short bf16x8;
typedef __attribute__((ext_vector_type(4))) float f32x4;

__device__ __forceinline__ float toF(float v) { return v; }
__device__ __forceinline__ float toF(bf16 v)  { return __bfloat162float(v); }

// ================= CSR build =================
__global__ void k_zero_i(int* __restrict__ p, int n) {
    int i = blockIdx.x * 256 + threadIdx.x;
    if (i < n) p[i] = 0;
}

__global__ void k_hist(const int* __restrict__ ei, int E, int* __restrict__ cnt) {
    int e = blockIdx.x * 256 + threadIdx.x;
    if (e < E) atomicAdd(&cnt[ei[E + e]], 1);
}

__global__ void k_scan1(const int* __restrict__ cnt, int n, int* __restrict__ bsum) {
    __shared__ int sh[256];
    int i = blockIdx.x * 256 + threadIdx.x;
    sh[threadIdx.x] = (i < n) ? cnt[i] : 0;
    __syncthreads();
    for (int o = 128; o; o >>= 1) {
        if (threadIdx.x < o) sh[threadIdx.x] += sh[threadIdx.x + o];
        __syncthreads();
    }
    if (threadIdx.x == 0) bsum[blockIdx.x] = sh[0];
}

__global__ void k_scan2(int* __restrict__ bsum, int nb) {  // 1 block
    __shared__ int sh[256];
    __shared__ int carry;
    if (threadIdx.x == 0) carry = 0;
    __syncthreads();
    for (int base = 0; base < nb; base += 256) {
        int i = base + threadIdx.x;
        int v = (i < nb) ? bsum[i] : 0;
        sh[threadIdx.x] = v;
        __syncthreads();
        for (int o = 1; o < 256; o <<= 1) {
            int t = (threadIdx.x >= o) ? sh[threadIdx.x - o] : 0;
            __syncthreads();
            sh[threadIdx.x] += t;
            __syncthreads();
        }
        if (i < nb) bsum[i] = carry + sh[threadIdx.x] - v;  // exclusive
        __syncthreads();
        if (threadIdx.x == 255) carry += sh[255];
        __syncthreads();
    }
}

__global__ void k_scan3(const int* __restrict__ cnt, int n, const int* __restrict__ bsum,
                        int* __restrict__ out) {
    __shared__ int sh[256];
    int i = blockIdx.x * 256 + threadIdx.x;
    int v = (i < n) ? cnt[i] : 0;
    sh[threadIdx.x] = v;
    __syncthreads();
    for (int o = 1; o < 256; o <<= 1) {
        int t = (threadIdx.x >= o) ? sh[threadIdx.x - o] : 0;
        __syncthreads();
        sh[threadIdx.x] += t;
        __syncthreads();
    }
    if (i <= n) out[i] = bsum[blockIdx.x] + sh[threadIdx.x] - v;
}

__global__ void k_fill(const int* __restrict__ ei, int E, const int* __restrict__ rowptr,
                       int* __restrict__ cnt, int* __restrict__ col) {
    int e = blockIdx.x * 256 + threadIdx.x;
    if (e >= E) return;
    int d = ei[E + e];
    int pos = rowptr[d] + atomicAdd(&cnt[d], 1);
    col[pos] = ei[e];
}

// ================= weight prep =================
// wa[lr*512 + k*8 + j]; j 0..3 src head j, 4..7 dst head j-4
__global__ void k_wa(const float* __restrict__ lin_w, const float* __restrict__ att_s,
                     const float* __restrict__ att_d, float* __restrict__ wa) {
    int i = blockIdx.x * 256 + threadIdx.x;
    if (i >= 2 * 7 * 64 * 8) return;
    int j = i & 7;
    int k = (i >> 3) & 63;
    int lr = i >> 9;
    int h = j & 3;
    const float* a = (j < 4 ? att_s : att_d) + lr * 64 + h * 16;
    const float* Wp = lin_w + (size_t)lr * 4096 + k * 64 + h * 16;
    float s = 0.f;
#pragma unroll
    for (int c = 0; c < 16; c++) s += Wp[c] * a[c];
    wa[i] = s;
}

// wt: per (l,r): [2][64][64] bf16, transposed (Wt[c][k]), hi + lo split
__global__ void k_wt(const float* __restrict__ lin_w, bf16* __restrict__ wt) {
    int i = blockIdx.x * 256 + threadIdx.x;
    if (i >= 14 * 4096) return;
    int lr = i >> 12;
    int kc = i & 4095;
    int k = kc >> 6, c = kc & 63;
    float v = lin_w[(size_t)lr * 4096 + k * 64 + c];
    bf16 hi = __float2bfloat16(v);
    float rem = v - __bfloat162float(hi);
    wt[(size_t)lr * 8192 + c * 64 + k] = hi;
    wt[(size_t)lr * 8192 + 4096 + c * 64 + k] = __float2bfloat16(rem);
}

// ================= input projection (fp32 VALU, runs once) =================
__global__ void k_proj(const float* __restrict__ x, const float* __restrict__ W,
                       const float* __restrict__ bias, bf16* __restrict__ out,
                       int N, int K) {
    __shared__ float Ws[64 * 64];
    __shared__ float xs[32 * 64];
    int tid = threadIdx.x;
    int r0 = blockIdx.x << 5;
    for (int i = tid; i < K * 64; i += 256) Ws[i] = W[i];
    for (int i = tid; i < 32 * K; i += 256) {
        int row = i / K, col = i - row * K;
        int n = r0 + row;
        xs[(row << 6) + col] = (n < N) ? x[(size_t)n * K + col] : 0.f;
    }
    __syncthreads();
    int c = tid & 63;
    float bv = bias[c];
    for (int rr = tid >> 6; rr < 32; rr += 4) {
        int n = r0 + rr;
        if (n >= N) return;
        float acc = bv;
#pragma unroll 16
        for (int k = 0; k < K; k++) acc = fmaf(xs[(rr << 6) + k], Ws[(k << 6) + c], acc);
        out[(size_t)n * 64 + c] = __float2bfloat16(acc);
    }
}

// ================= MFMA projection + fused alphas =================
__global__ void k_pmfma(const bf16* __restrict__ x, const bf16* __restrict__ wt,
                        const float* __restrict__ avs_p, const float* __restrict__ avd_p,
                        bf16* __restrict__ hs, float* __restrict__ aS, float* __restrict__ aD,
                        int N) {
    int w = threadIdx.x >> 6, lane = threadIdx.x & 63;
    int m = lane & 15, kq = lane >> 4;
    int r0 = blockIdx.x * 64 + w * 16;
    bf16x8 a0 = {}, a1 = {};
    int row = r0 + m;
    if (row < N) {
        a0 = *(const bf16x8*)(x + (size_t)row * 64 + kq * 8);
        a1 = *(const bf16x8*)(x + (size_t)row * 64 + 32 + kq * 8);
    }
#pragma unroll
    for (int nt = 0; nt < 4; nt++) {
        const bf16* wb  = wt + (nt * 16 + m) * 64 + kq * 8;
        const bf16* wbl = wb + 4096;
        bf16x8 bh0 = *(const bf16x8*)(wb);
        bf16x8 bh1 = *(const bf16x8*)(wb + 32);
        bf16x8 bl0 = *(const bf16x8*)(wbl);
        bf16x8 bl1 = *(const bf16x8*)(wbl + 32);
        f32x4 acc = {};
        acc = __builtin_amdgcn_mfma_f32_16x16x32_bf16(a0, bh0, acc, 0, 0, 0);
        acc = __builtin_amdgcn_mfma_f32_16x16x32_bf16(a0, bl0, acc, 0, 0, 0);
        acc = __builtin_amdgcn_mfma_f32_16x16x32_bf16(a1, bh1, acc, 0, 0, 0);
        acc = __builtin_amdgcn_mfma_f32_16x16x32_bf16(a1, bl1, acc, 0, 0, 0);
        float avsv = avs_p ? avs_p[nt * 16 + m] : 0.f;
        float avdv = avd_p ? avd_p[nt * 16 + m] : 0.f;
#pragma unroll
        for (int i = 0; i < 4; i++) {
            int rr = r0 + kq * 4 + i;
            if (rr < N) hs[(size_t)rr * 64 + nt * 16 + m] = __float2bfloat16(acc[i]);
            if (avs_p) {
                float ps = acc[i] * avsv;
                ps += __shfl_xor(ps, 1); ps += __shfl_xor(ps, 2);
                ps += __shfl_xor(ps, 4); ps += __shfl_xor(ps, 8);
                if (m == 0 && rr < N) aS[rr * 4 + nt] = ps;
            }
            if (avd_p) {
                float pd = acc[i] * avdv;
                pd += __shfl_xor(pd, 1); pd += __shfl_xor(pd, 2);
                pd += __shfl_xor(pd, 4); pd += __shfl_xor(pd, 8);
                if (m == 0 && rr < N) aD[rr * 4 + nt] = pd;
            }
        }
    }
}

// ================= alpha_dst GEMV (cross-type relations only) =================
__global__ void k_alpha(const bf16* __restrict__ x, const float* __restrict__ wa,
                        float* __restrict__ aD, int N) {
    __shared__ float xs[32 * 64];
    __shared__ float was[512];
    int tid = threadIdx.x;
    int r0 = blockIdx.x << 5;
    was[tid] = wa[tid];
    was[tid + 256] = wa[tid + 256];
    for (int i = tid; i < 2048; i += 256) {
        int row = i >> 6, col = i & 63;
        int n = r0 + row;
        xs[i] = (n < N) ? toF(x[(size_t)n * 64 + col]) : 0.f;
    }
    __syncthreads();
    int row = tid >> 3, j = tid & 7;
    int n = r0 + row;
    if (n >= N || j < 4) return;
    float acc = 0.f;
#pragma unroll
    for (int k = 0; k < 64; k++) acc = fmaf(xs[(row << 6) + k], was[(k << 3) + j], acc);
    aD[n * 4 + (j - 4)] = acc;
}

// ================= fused GAT aggregation: wave per dst node =================
// All cross-lane ops in wave-uniform control flow (no divergent shfls).
__device__ __forceinline__ void gat_rel(const int* __restrict__ rp, const int* __restrict__ col,
                                        const float* __restrict__ aS, const float* __restrict__ aD,
                                        const bf16* __restrict__ hs, int node, int lane,
                                        float& acc) {
    int beg = rp[node], end = rp[node + 1];
    int deg = end - beg;
    if (deg == 0) return;
    int h = lane & 3, j = lane >> 2;
    int hcl = lane >> 4;
    float ad = aD[node * 4 + h];
    if (deg <= 16) {
        // softmax weights held in registers (lane = edge*4+head)
        int s = 0;
        float a = -INFINITY;
        if (j < deg) {
            s = col[beg + j];
            a = aS[s * 4 + h] + ad;
            a = (a >= 0.f) ? a : 0.2f * a;
        }
        float mx = a;
        mx = fmaxf(mx, __shfl_xor(mx, 4));
        mx = fmaxf(mx, __shfl_xor(mx, 8));
        mx = fmaxf(mx, __shfl_xor(mx, 16));
        mx = fmaxf(mx, __shfl_xor(mx, 32));
        float ex = (j < deg) ? __expf(a - mx) : 0.f;
        float dn = ex;
        dn += __shfl_xor(dn, 4); dn += __shfl_xor(dn, 8);
        dn += __shfl_xor(dn, 16); dn += __shfl_xor(dn, 32);
        float w = ex / (dn + 1e-16f);
        // aggregation: lane = channel; uniform trip count, all lanes active
        for (int jj = 0; jj < deg; jj++) {
            int sj = __shfl(s, jj << 2);
            float wj = __shfl(w, (jj << 2) | hcl);
            acc = fmaf(toF(hs[(size_t)sj * 64 + lane]), wj, acc);
        }
    } else {
        float mx = -INFINITY;
        for (int i = beg + j; i < end; i += 16) {
            float a = aS[col[i] * 4 + h] + ad;
            a = (a >= 0.f) ? a : 0.2f * a;
            mx = fmaxf(mx, a);
        }
        mx = fmaxf(mx, __shfl_xor(mx, 4));
        mx = fmaxf(mx, __shfl_xor(mx, 8));
        mx = fmaxf(mx, __shfl_xor(mx, 16));
        mx = fmaxf(mx, __shfl_xor(mx, 32));
        float dn = 0.f;
        for (int i = beg + j; i < end; i += 16) {
            float a = aS[col[i] * 4 + h] + ad;
            a = (a >= 0.f) ? a : 0.2f * a;
            dn += __expf(a - mx);
        }
        dn += __shfl_xor(dn, 4); dn += __shfl_xor(dn, 8);
        dn += __shfl_xor(dn, 16); dn += __shfl_xor(dn, 32);
        float mh = __shfl(mx, hcl);
        float rdh = 1.f / (__shfl(dn, hcl) + 1e-16f);
        float adh = __shfl(ad, hcl);
        for (int i = beg; i < end; i++) {
            int s = col[i];
            float a = aS[s * 4 + hcl] + adh;
            a = (a >= 0.f) ? a : 0.2f * a;
            float w = __expf(a - mh) * rdh;
            acc = fmaf(toF(hs[(size_t)s * 64 + lane]), w, acc);
        }
    }
}

__global__ void k_gat(const int* rp0, const int* c0, const float* aS0, const float* aD0, const bf16* h0,
                      const int* rp1, const int* c1, const float* aS1, const float* aD1, const bf16* h1,
                      const int* rp2, const int* c2p, const float* aS2, const float* aD2, const bf16* h2,
                      const float* __restrict__ cb, int b0, int b1, int b2,
                      bf16* __restrict__ out, int Nd) {
    int node = blockIdx.x * 4 + (threadIdx.x >> 6);
    if (node >= Nd) return;
    int lane = threadIdx.x & 63;
    float acc = cb[b0 * 64 + lane];
    if (b1 >= 0) acc += cb[b1 * 64 + lane];
    if (b2 >= 0) acc += cb[b2 * 64 + lane];
    gat_rel(rp0, c0, aS0, aD0, h0, node, lane, acc);
    if (rp1) gat_rel(rp1, c1, aS1, aD1, h1, node, lane, acc);
    if (rp2) gat_rel(rp2, c2p, aS2, aD2, h2, node, lane, acc);
    out[(size_t)node * 64 + lane] = __float2bfloat16(acc > 0.f ? acc : 0.f);
}

// ================= classifier =================
__global__ void k_cls(const bf16* __restrict__ t, const float* __restrict__ w1,
                      const float* __restrict__ b1, const float* __restrict__ w2,
                      const float* __restrict__ b2, float* __restrict__ out) {
    __shared__ float w1s[64 * 32];
    __shared__ float w2s[64];
    __shared__ float b1s[32];
    __shared__ float b2s[2];
    __shared__ float ts[8 * 64];
    int tid = threadIdx.x;
    for (int i = tid; i < 2048; i += 256) w1s[i] = w1[i];
    if (tid < 64) w2s[tid] = w2[tid];
    if (tid < 32) b1s[tid] = b1[tid];
    if (tid < 2) b2s[tid] = b2[tid];
    int n0 = blockIdx.x << 3;
    for (int i = tid; i < 512; i += 256) {
        int row = i >> 6, col = i & 63;
        ts[i] = toF(t[(size_t)(n0 + row) * 64 + col]);
    }
    __syncthreads();
    int lane = tid & 31;
    int row = tid >> 5;
    float h = b1s[lane];
#pragma unroll 8
    for (int k = 0; k < 64; k++) h = fmaf(ts[(row << 6) + k], w1s[(k << 5) + lane], h);
    h = h > 0.f ? h : 0.f;
    float o0 = h * w2s[lane * 2 + 0];
    float o1 = h * w2s[lane * 2 + 1];
#pragma unroll
    for (int off = 16; off; off >>= 1) {
        o0 += __shfl_down(o0, off, 32);
        o1 += __shfl_down(o1, off, 32);
    }
    if (lane == 0) {
        int n = n0 + row;
        out[(size_t)n * 2 + 0] = o0 + b2s[0];
        out[(size_t)n * 2 + 1] = o1 + b2s[1];
    }
}

extern "C" void kernel_launch(void* const* d_in, const int* in_sizes, int n_in,
                              void* d_out, int out_size, void* d_ws, size_t ws_size,
                              hipStream_t stream) {
    (void)n_in; (void)out_size;
    const float* x_user  = (const float*)d_in[0];
    const float* x_tx    = (const float*)d_in[1];
    const float* x_merch = (const float*)d_in[2];
    const int* ei[7];
    int E[7];
    for (int r = 0; r < 7; r++) { ei[r] = (const int*)d_in[3 + r]; E[r] = in_sizes[3 + r] / 2; }
    const float* Win_user  = (const float*)d_in[10];
    const float* bin_user  = (const float*)d_in[11];
    const float* Win_tx    = (const float*)d_in[12];
    const float* bin_tx    = (const float*)d_in[13];
    const float* Win_merch = (const float*)d_in[14];
    const float* bin_merch = (const float*)d_in[15];
    const float* lin_w     = (const float*)d_in[16];
    const float* att_src   = (const float*)d_in[17];
    const float* att_dst   = (const float*)d_in[18];
    const float* conv_bias = (const float*)d_in[19];
    const float* cls_w1    = (const float*)d_in[20];
    const float* cls_b1    = (const float*)d_in[21];
    const float* cls_w2    = (const float*)d_in[22];
    const float* cls_b2    = (const float*)d_in[23];

    const int src_type[7] = {0, 1, 2, 1, 0, 2, 1};
    const int dst_type[7] = {1, 0, 1, 2, 0, 2, 1};
    const int N_of[3] = {NU, NT, NM};

    // ---- workspace layout ----
    size_t off = 0;
    auto alloc = [&](size_t bytes) { size_t q = off; off += (bytes + 255) & ~(size_t)255; return q; };
    size_t o_a[3], o_b[3], o_hs[3], o_aS[3];
    for (int tpe = 0; tpe < 3; tpe++) o_a[tpe]  = alloc((size_t)N_of[tpe] * 64 * 2);
    for (int tpe = 0; tpe < 3; tpe++) o_b[tpe]  = alloc((size_t)N_of[tpe] * 64 * 2);
    for (int tpe = 0; tpe < 3; tpe++) o_hs[tpe] = alloc((size_t)N_of[tpe] * 64 * 2);
    for (int tpe = 0; tpe < 3; tpe++) o_aS[tpe] = alloc((size_t)N_of[tpe] * 4 * 4);
    size_t o_aD[3];
    for (int jj = 0; jj < 3; jj++) o_aD[jj] = alloc((size_t)NT * 4 * 4);
    size_t o_rp[7], o_col[7];
    for (int r = 0; r < 7; r++) o_rp[r]  = alloc(((size_t)N_of[dst_type[r]] + 1) * 4);
    for (int r = 0; r < 7; r++) o_col[r] = alloc((size_t)E[r] * 4);
    size_t o_cnt  = alloc((size_t)NT * 4);
    size_t o_bsum = alloc((size_t)4096 * 4);
    size_t o_wa   = alloc((size_t)2 * 7 * 64 * 8 * 4);
    size_t o_wt   = alloc((size_t)14 * 8192 * 2);
    if (off > ws_size) return;  // fail cleanly

    char* base = (char*)d_ws;
    bf16* A[3], *B[3], *hsS[3];
    float* aSS[3];
    for (int tpe = 0; tpe < 3; tpe++) {
        A[tpe] = (bf16*)(base + o_a[tpe]);
        B[tpe] = (bf16*)(base + o_b[tpe]);
        hsS[tpe] = (bf16*)(base + o_hs[tpe]);
        aSS[tpe] = (float*)(base + o_aS[tpe]);
    }
    float* aDS[3];
    for (int jj = 0; jj < 3; jj++) aDS[jj] = (float*)(base + o_aD[jj]);
    int* rp[7]; int* col[7];
    for (int r = 0; r < 7; r++) { rp[r] = (int*)(base + o_rp[r]); col[r] = (int*)(base + o_col[r]); }
    int* cnt  = (int*)(base + o_cnt);
    int* bsum = (int*)(base + o_bsum);
    float* wa = (float*)(base + o_wa);
    bf16* wt  = (bf16*)(base + o_wt);

    // ---- build CSR per relation ----
    for (int r = 0; r < 7; r++) {
        int Nd = N_of[dst_type[r]];
        int nb = (Nd + 1 + 255) / 256;
        k_zero_i<<<(Nd + 255) / 256, 256, 0, stream>>>(cnt, Nd);
        k_hist<<<(E[r] + 255) / 256, 256, 0, stream>>>(ei[r], E[r], cnt);
        k_scan1<<<nb, 256, 0, stream>>>(cnt, Nd, bsum);
        k_scan2<<<1, 256, 0, stream>>>(bsum, nb);
        k_scan3<<<nb, 256, 0, stream>>>(cnt, Nd, bsum, rp[r]);
        k_zero_i<<<(Nd + 255) / 256, 256, 0, stream>>>(cnt, Nd);
        k_fill<<<(E[r] + 255) / 256, 256, 0, stream>>>(ei[r], E[r], rp[r], cnt, col[r]);
    }

    k_wa<<<(7168 + 255) / 256, 256, 0, stream>>>(lin_w, att_src, att_dst, wa);
    k_wt<<<(14 * 4096 + 255) / 256, 256, 0, stream>>>(lin_w, wt);
    k_proj<<<(NU + 31) / 32, 256, 0, stream>>>(x_user, Win_user, bin_user, A[0], NU, 32);
    k_proj<<<(NT + 31) / 32, 256, 0, stream>>>(x_tx, Win_tx, bin_tx, A[1], NT, 64);
    k_proj<<<(NM + 31) / 32, 256, 0, stream>>>(x_merch, Win_merch, bin_merch, A[2], NM, 16);

    const int grp_dst[3]     = {1, 0, 2};
    const int grp_rels[3][3] = {{0, 2, 6}, {1, 4, -1}, {3, 5, -1}};

    for (int l = 0; l < 2; l++) {
        bf16** cur = (l == 0) ? A : B;
        bf16** nxt = (l == 0) ? B : A;
        const float* cb = conv_bias + (size_t)l * 7 * 64;
        for (int g = 0; g < 3; g++) {
            int dt = grp_dst[g];
            int Nd = N_of[dt];
            const int* grp = grp_rels[g];
            for (int jj = 0; jj < 3; jj++) {
                int r = grp[jj];
                if (r < 0) break;
                int st = src_type[r];
                int lr = l * 7 + r;
                const bf16* wtp  = wt + (size_t)lr * 8192;
                const float* avs = att_src + (size_t)lr * 64;
                const float* avd = att_dst + (size_t)lr * 64;
                const float* war = wa + (size_t)lr * 512;
                if (st == dt) {
                    k_pmfma<<<(N_of[st] + 63) / 64, 256, 0, stream>>>(
                        cur[st], wtp, avs, avd, hsS[st], aSS[st], aDS[jj], N_of[st]);
                } else {
                    k_pmfma<<<(N_of[st] + 63) / 64, 256, 0, stream>>>(
                        cur[st], wtp, avs, nullptr, hsS[st], aSS[st], nullptr, N_of[st]);
                    k_alpha<<<(Nd + 31) / 32, 256, 0, stream>>>(cur[dt], war, aDS[jj], Nd);
                }
            }
            int r0 = grp[0], r1 = grp[1], r2 = grp[2];
            k_gat<<<(Nd + 3) / 4, 256, 0, stream>>>(
                rp[r0], col[r0], aSS[src_type[r0]], aDS[0], hsS[src_type[r0]],
                r1 >= 0 ? rp[r1] : nullptr, r1 >= 0 ? col[r1] : nullptr,
                r1 >= 0 ? aSS[src_type[r1]] : nullptr, aDS[1], r1 >= 0 ? hsS[src_type[r1]] : nullptr,
                r2 >= 0 ? rp[r2] : nullptr, r2 >= 0 ? col[r2] : nullptr,
                r2 >= 0 ? aSS[src_type[r2]] : nullptr, aDS[2], r2 >= 0 ? hsS[src_type[r2]] : nullptr,
                cb, r0, r1, r2, nxt[dt], Nd);
        }
    }
    k_cls<<<NT / 8, 256, 0, stream>>>(A[1], cls_w1, cls_b1, cls_w2, cls_b2, (float*)d_out);
}